// Round 4
// baseline (478.025 us; speedup 1.0000x reference)
//
#include <hip/hip_runtime.h>
#include <cfloat>
#include <math.h>

#define B_ 8
#define C_ 256
#define C2_ (C_/2)            // uints (bf16 pairs) per pixel
#define H_ 128
#define W_ 128
#define N_ (H_*W_)            // 16384
#define NRAND 32
#define NHARD 96
#define NPOS 256
#define INV_TEMP (1.0f/0.07f)

typedef __attribute__((ext_vector_type(8))) short short8;   // 8 bf16 (4 VGPRs)
typedef __attribute__((ext_vector_type(4))) float f32x4;    // MFMA acc

__device__ __forceinline__ unsigned bf16rne(float x) {
    unsigned u = __float_as_uint(x);
    return (u + 0x7FFFu + ((u >> 16) & 1u)) >> 16;
}
__device__ __forceinline__ float blo(unsigned w) { return __uint_as_float(w << 16); }
__device__ __forceinline__ float bhi(unsigned w) { return __uint_as_float(w & 0xFFFF0000u); }

// ---------------------------------------------------------------------------
// kA v2: normalize rgb->rgbT and dep->depT (bf16 [n][c]).
// 128-px tiles; pass 1 reads one FULL 512B channel row per wave-instruction
// (float2/lane, 64 lanes) -> ssq + raw bf16 into 64KB XOR-swizzled LDS tile;
// pass 2 reads LDS columns (2-way conflicts = free), scales by invn, packs,
// stores 512B/pixel rows. Read granule 256B -> 512B is the whole point.
// ---------------------------------------------------------------------------
__global__ __launch_bounds__(256, 2) void kA_norm(
        const float* __restrict__ rgb, const float* __restrict__ dep,
        unsigned* __restrict__ rgbT, unsigned* __restrict__ depT) {
    __shared__ unsigned tileW[256 * 64];    // 64 KB: word (c, pp) = px{2pp,2pp+1}
    __shared__ float red[4][128];
    __shared__ float invn[128];
    int bi = blockIdx.x;
    int sel = bi & 1;                 // 0: rgb, 1: dep (interleaved for balance)
    int sub = bi >> 1;                // [0, 1024)
    int b   = sub >> 7;
    int p0  = (sub & 127) << 7;       // 128-px tile
    int t = threadIdx.x, q = t & 63, w = t >> 6;

    const float* src = (sel ? dep : rgb) + (size_t)b * C_ * N_ + p0;
    float ssx = 0.f, ssy = 0.f;
    #pragma unroll 8
    for (int k = 0; k < 64; ++k) {
        int c = w * 64 + k;
        float2 v = ((const float2*)(src + (size_t)c * N_))[q];
        ssx += v.x * v.x;
        ssy += v.y * v.y;
        tileW[c * 64 + (q ^ (c & 63))] = bf16rne(v.x) | (bf16rne(v.y) << 16);
    }
    red[w][2 * q]     = ssx;
    red[w][2 * q + 1] = ssy;
    __syncthreads();
    if (t < 128) {
        float s = red[0][t] + red[1][t] + red[2][t] + red[3][t];
        invn[t] = 1.0f / fmaxf(sqrtf(s), 1e-12f);
    }
    __syncthreads();
    // pass 2: thread = (px = t>>1, half = t&1); 128 channels each
    int px = t >> 1, half = t & 1, pp = t >> 2;
    float sc = invn[px];
    unsigned sh = (px & 1) * 16;
    uint4* dst = (uint4*)((sel ? depT : rgbT) + (size_t)(b * N_ + p0 + px) * C2_)
                 + half * 16;
    #pragma unroll
    for (int j4 = 0; j4 < 16; ++j4) {
        unsigned oo[4];
        #pragma unroll
        for (int e = 0; e < 4; ++e) {
            int c0 = half * 128 + j4 * 8 + e * 2;
            unsigned w0 = tileW[c0 * 64 + (pp ^ (c0 & 63))];
            unsigned w1 = tileW[(c0 + 1) * 64 + (pp ^ ((c0 + 1) & 63))];
            float f0 = __uint_as_float(((w0 >> sh) & 0xFFFFu) << 16) * sc;
            float f1 = __uint_as_float(((w1 >> sh) & 0xFFFFu) << 16) * sc;
            oo[e] = bf16rne(f0) | (bf16rne(f1) << 16);
        }
        dst[j4] = make_uint4(oo[0], oo[1], oo[2], oo[3]);
    }
}

// ---------------------------------------------------------------------------
// kB: merged k2 (even blocks) + k3 (odd blocks). Both depend only on kA;
// merging co-schedules k3's latency-bound gathers with k2's MFMA waves.
// ---------------------------------------------------------------------------
__global__ __launch_bounds__(256, 4) void kB_main(
        const unsigned* __restrict__ depT, const unsigned* __restrict__ rgbT,
        const float* __restrict__ coords, const int* __restrict__ rand_idx,
        const int* __restrict__ hoffu, const int* __restrict__ hoffv,
        float* __restrict__ lse_base, float* __restrict__ pos_out,
        float* __restrict__ maxneg_out, float* __restrict__ lse_hard,
        float* __restrict__ max_hard) {
    __shared__ __align__(16) unsigned char smem[16384];
    int t = threadIdx.x;

    if ((blockIdx.x & 1) == 0) {
        // ================= k2 part: per 64-pixel tile =================
        uint4* rs4 = (uint4*)smem;            // 16 KB rand bf16 / later sims f32
        int bi = blockIdx.x >> 1;
        int b  = bi >> 8;
        int p0 = (bi & 255) << 6;
        int lane = t & 63, w = t >> 6;
        int l15 = lane & 15, l4 = lane >> 4;

        // stage 32 rand vectors: 16B chunks, coalesced 512B per vector
        #pragma unroll
        for (int it = 0; it < 4; ++it) {
            int flat = it * 256 + t;
            int rn = flat >> 5, c8 = flat & 31;
            int idx = rand_idx[b * NRAND + rn];
            const uint4* src = (const uint4*)(rgbT + (size_t)(b * N_ + idx) * C2_);
            rs4[rn * 32 + (c8 ^ (rn & 7))] = src[c8];
        }

        // A-fragments straight from depT
        const short8* arow = (const short8*)(depT + (size_t)(b * N_ + p0 + (w << 4) + l15) * C2_);
        short8 afr[8];
        #pragma unroll
        for (int kc = 0; kc < 8; ++kc) afr[kc] = arow[kc * 4 + l4];

        // bilinear setup
        int px = t >> 2, g = t & 3;
        int n  = p0 + px;
        float xf = coords[(size_t)b * 2 * N_ + n];
        float yf = coords[(size_t)b * 2 * N_ + N_ + n];
        float x0 = floorf(xf), y0 = floorf(yf);
        float wx = xf - x0, wy = yf - y0;
        int ix = (int)x0 + (g & 1);
        int iy = (int)y0 + (g >> 1);
        float wgt = ((g & 1) ? wx : 1.f - wx) * ((g & 2) ? wy : 1.f - wy);
        if (ix < 0 || ix >= W_ || iy < 0 || iy >= H_) wgt = 0.f;
        int ixc = min(max(ix, 0), W_ - 1), iyc = min(max(iy, 0), H_ - 1);
        const uint4* nbr4 = (const uint4*)(rgbT + (size_t)(b * N_ + iyc * W_ + ixc) * C2_);

        __syncthreads();                      // rand staged

        f32x4 acc0 = {0.f, 0.f, 0.f, 0.f};
        f32x4 acc1 = {0.f, 0.f, 0.f, 0.f};
        const short8* rnd8 = (const short8*)rs4;
        #pragma unroll
        for (int kc = 0; kc < 8; ++kc) {
            int c8 = kc * 4 + l4;
            short8 b0 = rnd8[l15 * 32 + (c8 ^ (l15 & 7))];
            short8 b1 = rnd8[(16 + l15) * 32 + (c8 ^ (l15 & 7))];
            acc0 = __builtin_amdgcn_mfma_f32_16x16x32_bf16(afr[kc], b0, acc0, 0, 0, 0);
            acc1 = __builtin_amdgcn_mfma_f32_16x16x32_bf16(afr[kc], b1, acc1, 0, 0, 0);
        }

        // pos: dot(dep_px, nbr_g) on VALU
        float accN = 0.f;
        const uint4* drow = (const uint4*)(depT + (size_t)(b * N_ + n) * C2_);
        #pragma unroll 4
        for (int c8 = 0; c8 < 32; ++c8) {
            uint4 dq = drow[c8];
            uint4 rq = nbr4[c8];
            accN += blo(dq.x) * blo(rq.x) + bhi(dq.x) * bhi(rq.x)
                  + blo(dq.y) * blo(rq.y) + bhi(dq.y) * bhi(rq.y)
                  + blo(dq.z) * blo(rq.z) + bhi(dq.z) * bhi(rq.z)
                  + blo(dq.w) * blo(rq.w) + bhi(dq.w) * bhi(rq.w);
        }
        __syncthreads();                      // rs4 reusable

        float* simsF = (float*)rs4;
        #pragma unroll
        for (int r = 0; r < 4; ++r) {
            int prow = (w << 4) + (l4 << 2) + r;   // prow&3 == r
            int swn = r << 2;
            simsF[prow * 32 + (l15 ^ swn)]        = acc0[r];
            simsF[prow * 32 + (16 + (l15 ^ swn))] = acc1[r];
        }
        __syncthreads();

        const float scale = INV_TEMP;
        float pp = accN * wgt;
        pp += __shfl_xor(pp, 1, 4);
        pp += __shfl_xor(pp, 2, 4);
        float pos = pp * scale;
        const float4* sf = (const float4*)simsF;
        int fsw = px & 3;
        float4 ra = sf[px * 8 + ((g * 2) ^ fsw)];
        float4 rb = sf[px * 8 + (((g * 2) ^ fsw) ^ 1)];
        float r[8] = {ra.x, ra.y, ra.z, ra.w, rb.x, rb.y, rb.z, rb.w};
        float ml = -FLT_MAX;
        #pragma unroll
        for (int j = 0; j < 8; ++j) { r[j] *= scale; ml = fmaxf(ml, r[j]); }
        ml = fmaxf(ml, __shfl_xor(ml, 1, 4));
        ml = fmaxf(ml, __shfl_xor(ml, 2, 4));
        float mneg = ml;
        float mall = fmaxf(mneg, pos);
        float se = 0.f;
        #pragma unroll
        for (int j = 0; j < 8; ++j) se += expf(r[j] - mall);
        se += __shfl_xor(se, 1, 4);
        se += __shfl_xor(se, 2, 4);
        if (g == 0) {
            float lse = mall + logf(se + expf(pos - mall));
            size_t o = (size_t)b * N_ + n;
            lse_base[o]   = lse;
            pos_out[o]    = pos;
            maxneg_out[o] = mneg;
        }
    } else {
        // ================= k3 part: hard negatives =================
        float* dv  = (float*)smem;            // 256 floats
        float* sm_ = (float*)(smem + 1024);   // 4
        float* ss_ = (float*)(smem + 1040);   // 4
        int bp = blockIdx.x >> 1;
        int b = bp >> 8, p = bp & 255;
        int gy = (p >> 4) * 8, gx = (p & 15) * 8;
        int nn = gy * W_ + gx;
        if (t < 128) {
            unsigned wv = depT[(size_t)(b * N_ + nn) * C2_ + t];
            dv[2 * t]     = blo(wv);
            dv[2 * t + 1] = bhi(wv);
        }
        float pu = coords[(size_t)b * 2 * N_ + nn];
        float pv = coords[(size_t)b * 2 * N_ + N_ + nn];
        int iu = (int)fminf(fmaxf(pu, 0.f), (float)(W_ - 1));
        int iv = (int)fminf(fmaxf(pv, 0.f), (float)(H_ - 1));
        int h = t >> 1, half = t & 1;
        int ou = 1, ov = 0;
        if (t < 192) {
            ou = hoffu[((size_t)b * NHARD + h) * NPOS + p];
            ov = hoffv[((size_t)b * NHARD + h) * NPOS + p];
        }
        __syncthreads();
        float sim = -FLT_MAX;
        if (t < 192) {
            if (ou == 0 && ov == 0) ou = 1;
            int hu = min(max(iu + ou, 0), W_ - 1);
            int hv = min(max(iv + ov, 0), H_ - 1);
            const uint4* hvec = (const uint4*)(rgbT + (size_t)(b * N_ + hv * W_ + hu) * C2_)
                                + half * 16;
            const float4* dvv = (const float4*)dv + half * 32;
            float acc = 0.f;
            #pragma unroll 4
            for (int c8 = 0; c8 < 16; ++c8) {
                uint4 q = hvec[c8];
                float4 d0 = dvv[c8 * 2];
                float4 d1 = dvv[c8 * 2 + 1];
                acc += d0.x * blo(q.x) + d0.y * bhi(q.x)
                     + d0.z * blo(q.y) + d0.w * bhi(q.y)
                     + d1.x * blo(q.z) + d1.y * bhi(q.z)
                     + d1.z * blo(q.w) + d1.w * bhi(q.w);
            }
            sim = (acc + __shfl_xor(acc, 1, 2)) * INV_TEMP;
        }
        float m = sim;
        #pragma unroll
        for (int o = 32; o > 0; o >>= 1) m = fmaxf(m, __shfl_xor(m, o, 64));
        int wid = t >> 6;
        if ((t & 63) == 0) sm_[wid] = m;
        __syncthreads();
        float mm = fmaxf(fmaxf(sm_[0], sm_[1]), fmaxf(sm_[2], sm_[3]));
        float e = (t < 192 && half == 0) ? expf(sim - mm) : 0.f;
        #pragma unroll
        for (int o = 32; o > 0; o >>= 1) e += __shfl_xor(e, o, 64);
        if ((t & 63) == 0) ss_[wid] = e;
        __syncthreads();
        if (t == 0) {
            lse_hard[bp] = mm + logf(ss_[0] + ss_[1] + ss_[2] + ss_[3]);
            max_hard[bp] = mm;
        }
    }
}

// ---------------------------------------------------------------------------
// k4: masked reduction over all pixels (with grid-point hard fix-up) + final
// loss/accuracy computed by the last block to finish (atomic counter).
// ---------------------------------------------------------------------------
__global__ __launch_bounds__(256) void k4_reduce(
        const float* __restrict__ lse_base, const float* __restrict__ pos_sim,
        const float* __restrict__ max_neg, const float* __restrict__ mask,
        const float* __restrict__ lse_hard, const float* __restrict__ max_hard,
        float* __restrict__ acc, float* __restrict__ out) {
    int i = blockIdx.x * 256 + threadIdx.x;
    float l  = lse_base[i], ps = pos_sim[i], mn = max_neg[i], mk = mask[i];
    int b = i >> 14;
    int n = i & (N_ - 1);
    int y = n >> 7, x = n & 127;
    if (((y & 7) | (x & 7)) == 0) {
        int p = ((y >> 3) << 4) + (x >> 3);
        float lh = lse_hard[(b << 8) + p];
        float mh = max_hard[(b << 8) + p];
        float m = fmaxf(l, lh);
        l  = m + logf(expf(l - m) + expf(lh - m));
        mn = fmaxf(mn, mh);
    }
    float s0 = (l - ps) * mk;
    float s1 = (ps > mn && mk > 0.5f) ? 1.f : 0.f;
    float s2 = mk;
    #pragma unroll
    for (int o = 32; o > 0; o >>= 1) {
        s0 += __shfl_down(s0, o, 64);
        s1 += __shfl_down(s1, o, 64);
        s2 += __shfl_down(s2, o, 64);
    }
    __shared__ float r0[4], r1[4], r2[4];
    int wid = threadIdx.x >> 6;
    if ((threadIdx.x & 63) == 0) { r0[wid] = s0; r1[wid] = s1; r2[wid] = s2; }
    __syncthreads();
    if (threadIdx.x == 0) {
        atomicAdd(&acc[0], r0[0] + r0[1] + r0[2] + r0[3]);
        atomicAdd(&acc[1], r1[0] + r1[1] + r1[2] + r1[3]);
        atomicAdd(&acc[2], r2[0] + r2[1] + r2[2] + r2[3]);
        __threadfence();
        unsigned prev = atomicAdd((unsigned*)&acc[3], 1u);
        if (prev == gridDim.x - 1) {
            float t0 = atomicAdd(&acc[0], 0.f);
            float t1 = atomicAdd(&acc[1], 0.f);
            float t2 = atomicAdd(&acc[2], 0.f);
            float denom = fmaxf(t2, 1.0f);
            out[0] = t0 / denom;
            out[1] = t1 / denom * 100.0f;
        }
    }
}

extern "C" void kernel_launch(void* const* d_in, const int* in_sizes, int n_in,
                              void* d_out, int out_size, void* d_ws, size_t ws_size,
                              hipStream_t stream) {
    const float* rgb     = (const float*)d_in[0];
    const float* dep     = (const float*)d_in[1];
    const float* coords  = (const float*)d_in[2];
    const float* mask    = (const float*)d_in[3];
    const int*   rand_i  = (const int*)d_in[4];
    const int*   hoffu   = (const int*)d_in[5];
    const int*   hoffv   = (const int*)d_in[6];
    float* out = (float*)d_out;
    char*  ws  = (char*)d_ws;

    const size_t RGBT_B = (size_t)B_ * N_ * C_ * 2;      // bf16: 64 MiB
    const size_t PIX_B  = (size_t)B_ * N_ * 4;           // 512 KiB
    unsigned* rgbT  = (unsigned*)ws;
    unsigned* depT  = (unsigned*)(ws + RGBT_B);
    float* lse_base = (float*)(ws + 2 * RGBT_B);
    float* pos_sim  = (float*)(ws + 2 * RGBT_B + PIX_B);
    float* max_neg  = (float*)(ws + 2 * RGBT_B + 2 * PIX_B);
    float* lse_hard = (float*)(ws + 2 * RGBT_B + 3 * PIX_B);
    float* max_hard = (float*)(ws + 2 * RGBT_B + 3 * PIX_B + 8192);
    float* acc      = (float*)(ws + 2 * RGBT_B + 3 * PIX_B + 2 * 8192);

    hipMemsetAsync(acc, 0, 16, stream);
    kA_norm<<<2 * B_ * (N_ / 128), 256, 0, stream>>>(rgb, dep, rgbT, depT);
    kB_main<<<2 * B_ * (N_ / 64), 256, 0, stream>>>(depT, rgbT, coords, rand_i,
                                                    hoffu, hoffv, lse_base,
                                                    pos_sim, max_neg,
                                                    lse_hard, max_hard);
    k4_reduce<<<(B_ * N_) / 256, 256, 0, stream>>>(lse_base, pos_sim, max_neg,
                                                   mask, lse_hard, max_hard,
                                                   acc, out);
}

// Round 5
// 446.418 us; speedup vs baseline: 1.0708x; 1.0708x over previous
//
#include <hip/hip_runtime.h>
#include <cfloat>
#include <math.h>

#define B_ 8
#define C_ 256
#define C2_ (C_/2)            // uints (bf16 pairs) per pixel
#define H_ 128
#define W_ 128
#define N_ (H_*W_)            // 16384
#define NRAND 32
#define NHARD 96
#define NPOS 256
#define INV_TEMP (1.0f/0.07f)

typedef __attribute__((ext_vector_type(8))) short short8;   // 8 bf16 (4 VGPRs)
typedef __attribute__((ext_vector_type(4))) float f32x4;    // MFMA acc

__device__ __forceinline__ unsigned bf16rne(float x) {
    unsigned u = __float_as_uint(x);
    return (u + 0x7FFFu + ((u >> 16) & 1u)) >> 16;
}
__device__ __forceinline__ float blo(unsigned w) { return __uint_as_float(w << 16); }
__device__ __forceinline__ float bhi(unsigned w) { return __uint_as_float(w & 0xFFFF0000u); }

// ---------------------------------------------------------------------------
// k1: normalize rgb along C, write transposed bf16 rgbT[b][n][c] (packed u32).
// Register-resident 64ch/thread across the norm reduction; 32KB swizzled LDS
// bounce; fully coalesced uint4 stores. (best measured version, round 2)
// ---------------------------------------------------------------------------
__global__ __launch_bounds__(256) void k1_rgb_norm_T(const float* __restrict__ rgb,
                                                     unsigned* __restrict__ rgbT) {
    __shared__ __align__(16) uint4 bounce[64 * 32];   // 32 KB bf16 [px][ch]
    __shared__ float red[4][64];
    __shared__ float invn[64];
    int bi = blockIdx.x;
    int b  = bi >> 8;                 // 256 tiles per batch
    int p0 = (bi & 255) << 6;
    int t  = threadIdx.x;
    int lane = t & 63, w = t >> 6;

    const float* src = rgb + (size_t)b * C_ * N_ + p0 + lane;
    float v[64];
    float ssq = 0.f;
    #pragma unroll
    for (int k = 0; k < 64; ++k) {
        v[k] = src[(size_t)(w * 64 + k) * N_];
        ssq += v[k] * v[k];
    }
    red[w][lane] = ssq;
    __syncthreads();
    if (t < 64) {
        float s = red[0][t] + red[1][t] + red[2][t] + red[3][t];
        invn[t] = 1.0f / fmaxf(sqrtf(s), 1e-12f);
    }
    __syncthreads();
    float sc = invn[lane];
    int swz = lane & 7;
    #pragma unroll
    for (int j = 0; j < 8; ++j) {
        uint4 q;
        q.x = bf16rne(v[8 * j + 0] * sc) | (bf16rne(v[8 * j + 1] * sc) << 16);
        q.y = bf16rne(v[8 * j + 2] * sc) | (bf16rne(v[8 * j + 3] * sc) << 16);
        q.z = bf16rne(v[8 * j + 4] * sc) | (bf16rne(v[8 * j + 5] * sc) << 16);
        q.w = bf16rne(v[8 * j + 6] * sc) | (bf16rne(v[8 * j + 7] * sc) << 16);
        bounce[lane * 32 + ((w * 8 + j) ^ swz)] = q;
    }
    __syncthreads();
    uint4* dst = (uint4*)(rgbT + (size_t)(b * N_ + p0) * C2_);
    #pragma unroll
    for (int it = 0; it < 8; ++it) {
        int idx = it * 256 + t;
        int px = idx >> 5, j = idx & 31;
        dst[idx] = bounce[px * 32 + (j ^ (px & 7))];
    }
}

// ---------------------------------------------------------------------------
// k2: per 64-pixel tile (round-1 structure, best measured 83us) PLUS the
// hard-negative work fused into the 256 blocks owning grid rows (y%8==0):
// their dep4 LDS tile + invn already hold everything k3 needed, so the
// separate k3 launch (and its depG buffer / dep re-read) is eliminated.
// ---------------------------------------------------------------------------
__global__ __launch_bounds__(256) void k2_main(
        const float* __restrict__ dep, const unsigned* __restrict__ rgbT,
        const float* __restrict__ coords, const int* __restrict__ rand_idx,
        const int* __restrict__ hoffu, const int* __restrict__ hoffv,
        float* __restrict__ lse_base, float* __restrict__ pos_out,
        float* __restrict__ maxneg_out, float* __restrict__ lse_hard,
        float* __restrict__ max_hard) {
    __shared__ __align__(16) uint4 dep4[64 * 32];   // 32 KB bf16 [px][ch], swizzled
    __shared__ __align__(16) uint4 rs4[32 * 32];    // 16 KB rand bf16 / later sims f32[64][32]
    __shared__ float red[4][64];
    __shared__ float invn[64];
    int bi = blockIdx.x;
    int b  = bi >> 8;
    int p0 = (bi & 255) << 6;
    int t  = threadIdx.x;
    int lane = t & 63, w = t >> 6;

    // ---- stage 32 rand vectors: 16B gather chunks, coalesced 512B per vector
    #pragma unroll
    for (int it = 0; it < 4; ++it) {
        int flat = it * 256 + t;
        int rn = flat >> 5, c8 = flat & 31;
        int idx = rand_idx[b * NRAND + rn];
        const uint4* src = (const uint4*)(rgbT + (size_t)(b * N_ + idx) * C2_);
        rs4[rn * 32 + (c8 ^ (rn & 7))] = src[c8];
    }

    // ---- stage dep: thread -> pixel p0+lane, channels [64w, 64w+64)
    const float* depb = dep + (size_t)b * C_ * N_ + p0 + lane;
    float ssq = 0.f;
    int psw = lane & 7;
    #pragma unroll 2
    for (int i = 0; i < 8; ++i) {
        int c0 = w * 64 + i * 8;
        float v[8];
        #pragma unroll
        for (int k = 0; k < 8; ++k) {
            v[k] = depb[(size_t)(c0 + k) * N_];
            ssq += v[k] * v[k];
        }
        uint4 q;
        q.x = bf16rne(v[0]) | (bf16rne(v[1]) << 16);
        q.y = bf16rne(v[2]) | (bf16rne(v[3]) << 16);
        q.z = bf16rne(v[4]) | (bf16rne(v[5]) << 16);
        q.w = bf16rne(v[6]) | (bf16rne(v[7]) << 16);
        dep4[lane * 32 + ((w * 8 + i) ^ psw)] = q;
    }
    red[w][lane] = ssq;

    // ---- bilinear setup (issue coord loads before the barrier)
    int px = t >> 2, g = t & 3;
    int n  = p0 + px;
    float xf = coords[(size_t)b * 2 * N_ + n];
    float yf = coords[(size_t)b * 2 * N_ + N_ + n];
    float x0 = floorf(xf), y0 = floorf(yf);
    float wx = xf - x0, wy = yf - y0;
    int ix = (int)x0 + (g & 1);
    int iy = (int)y0 + (g >> 1);
    float wgt = ((g & 1) ? wx : 1.f - wx) * ((g & 2) ? wy : 1.f - wy);
    if (ix < 0 || ix >= W_ || iy < 0 || iy >= H_) wgt = 0.f;
    int ixc = min(max(ix, 0), W_ - 1), iyc = min(max(iy, 0), H_ - 1);
    const uint4* nbr4 = (const uint4*)(rgbT + (size_t)(b * N_ + iyc * W_ + ixc) * C2_);

    __syncthreads();                          // all LDS staged
    if (t < 64) {
        float s = red[0][t] + red[1][t] + red[2][t] + red[3][t];
        invn[t] = 1.0f / fmaxf(sqrtf(s), 1e-12f);
    }

    // ---- MFMA: A = dep rows (M=px), B = rand vectors (N=rand), K=256
    f32x4 acc0 = {0.f, 0.f, 0.f, 0.f};
    f32x4 acc1 = {0.f, 0.f, 0.f, 0.f};
    int l15 = lane & 15, l4 = lane >> 4;
    int pxA = (w << 4) + l15;
    const short8* lds8 = (const short8*)dep4;
    const short8* rnd8 = (const short8*)rs4;
    #pragma unroll
    for (int kc = 0; kc < 8; ++kc) {
        int c8 = kc * 4 + l4;
        short8 a  = lds8[pxA * 32 + (c8 ^ (pxA & 7))];
        short8 b0 = rnd8[l15 * 32 + (c8 ^ (l15 & 7))];
        short8 b1 = rnd8[(16 + l15) * 32 + (c8 ^ (l15 & 7))];
        acc0 = __builtin_amdgcn_mfma_f32_16x16x32_bf16(a, b0, acc0, 0, 0, 0);
        acc1 = __builtin_amdgcn_mfma_f32_16x16x32_bf16(a, b1, acc1, 0, 0, 0);
    }

    // ---- pos: dot(dep_px, nbr_g) on VALU (bf16 unpack)
    float accN = 0.f;
    const uint4* drow = dep4 + (size_t)px * 32;
    int dsw = px & 7;
    #pragma unroll 4
    for (int c8 = 0; c8 < 32; ++c8) {
        uint4 dq = drow[c8 ^ dsw];
        uint4 rq = nbr4[c8];
        accN += blo(dq.x) * blo(rq.x) + bhi(dq.x) * bhi(rq.x)
              + blo(dq.y) * blo(rq.y) + bhi(dq.y) * bhi(rq.y)
              + blo(dq.z) * blo(rq.z) + bhi(dq.z) * bhi(rq.z)
              + blo(dq.w) * blo(rq.w) + bhi(dq.w) * bhi(rq.w);
    }
    __syncthreads();                          // MFMA+pos reads done; rs4 reusable

    // ---- dump raw sims -> rs4 as f32 [64][32], n-index XOR'd by (prow&3)<<2
    float* simsF = (float*)rs4;
    #pragma unroll
    for (int r = 0; r < 4; ++r) {
        int prow = (w << 4) + (l4 << 2) + r;   // prow&3 == r
        int swn = r << 2;
        simsF[prow * 32 + (l15 ^ swn)]        = acc0[r];
        simsF[prow * 32 + (16 + (l15 ^ swn))] = acc1[r];
    }
    __syncthreads();

    // ---- epilogue per (px, g): thread g owns rand [8g, 8g+8)
    float scale = invn[px] * INV_TEMP;
    float pp = accN * wgt;
    pp += __shfl_xor(pp, 1, 4);
    pp += __shfl_xor(pp, 2, 4);
    float pos = pp * scale;
    const float4* sf = (const float4*)simsF;
    int fsw = px & 3;
    float4 ra = sf[px * 8 + ((g * 2) ^ fsw)];
    float4 rb = sf[px * 8 + (((g * 2) ^ fsw) ^ 1)];
    float r[8] = {ra.x, ra.y, ra.z, ra.w, rb.x, rb.y, rb.z, rb.w};
    float ml = -FLT_MAX;
    #pragma unroll
    for (int j = 0; j < 8; ++j) { r[j] *= scale; ml = fmaxf(ml, r[j]); }
    ml = fmaxf(ml, __shfl_xor(ml, 1, 4));
    ml = fmaxf(ml, __shfl_xor(ml, 2, 4));
    float mneg = ml;
    float mall = fmaxf(mneg, pos);
    float se = 0.f;
    #pragma unroll
    for (int j = 0; j < 8; ++j) se += expf(r[j] - mall);
    se += __shfl_xor(se, 1, 4);
    se += __shfl_xor(se, 2, 4);
    if (g == 0) {
        float lse = mall + logf(se + expf(pos - mall));
        size_t o = (size_t)b * N_ + n;
        lse_base[o]   = lse;
        pos_out[o]    = pos;
        maxneg_out[o] = mneg;
    }

    // ---- fused hard negatives: blocks on grid rows (y%8==0) own 8 grid
    // points each. 32 workers per grid point, 3 hard negatives per worker.
    // Uses the raw-bf16 dep4 row (LDS broadcast) + invn (no depG, no re-read).
    if (((bi & 255) & 14) == 0) {
        int gp = t >> 5, wk = t & 31;
        int y  = p0 >> 7;
        int gx = (p0 & 127) + gp * 8;
        int gpx = gp * 8;                     // local pixel of the grid point
        int pidx = ((y >> 3) << 4) + (gx >> 3);
        int nn = y * W_ + gx;
        float pu = coords[(size_t)b * 2 * N_ + nn];
        float pv = coords[(size_t)b * 2 * N_ + N_ + nn];
        int iu = (int)fminf(fmaxf(pu, 0.f), (float)(W_ - 1));
        int iv = (int)fminf(fmaxf(pv, 0.f), (float)(H_ - 1));
        const uint4* hv0; const uint4* hv1; const uint4* hv2;
        {
            int h0 = wk, h1 = wk + 32, h2 = wk + 64;
            int ou0 = hoffu[((size_t)b * NHARD + h0) * NPOS + pidx];
            int ov0 = hoffv[((size_t)b * NHARD + h0) * NPOS + pidx];
            int ou1 = hoffu[((size_t)b * NHARD + h1) * NPOS + pidx];
            int ov1 = hoffv[((size_t)b * NHARD + h1) * NPOS + pidx];
            int ou2 = hoffu[((size_t)b * NHARD + h2) * NPOS + pidx];
            int ov2 = hoffv[((size_t)b * NHARD + h2) * NPOS + pidx];
            if (ou0 == 0 && ov0 == 0) ou0 = 1;
            if (ou1 == 0 && ov1 == 0) ou1 = 1;
            if (ou2 == 0 && ov2 == 0) ou2 = 1;
            int u0 = min(max(iu + ou0, 0), W_ - 1), v0 = min(max(iv + ov0, 0), H_ - 1);
            int u1 = min(max(iu + ou1, 0), W_ - 1), v1 = min(max(iv + ov1, 0), H_ - 1);
            int u2 = min(max(iu + ou2, 0), W_ - 1), v2 = min(max(iv + ov2, 0), H_ - 1);
            hv0 = (const uint4*)(rgbT + (size_t)(b * N_ + v0 * W_ + u0) * C2_);
            hv1 = (const uint4*)(rgbT + (size_t)(b * N_ + v1 * W_ + u1) * C2_);
            hv2 = (const uint4*)(rgbT + (size_t)(b * N_ + v2 * W_ + u2) * C2_);
        }
        float a0 = 0.f, a1 = 0.f, a2 = 0.f;
        const uint4* dr = dep4 + (size_t)gpx * 32;
        int dsw2 = gpx & 7;
        #pragma unroll 4
        for (int c8 = 0; c8 < 32; ++c8) {
            uint4 dq = dr[c8 ^ dsw2];         // same addr across 32 workers: broadcast
            float d0 = blo(dq.x), d1 = bhi(dq.x), d2 = blo(dq.y), d3 = bhi(dq.y);
            float d4 = blo(dq.z), d5 = bhi(dq.z), d6 = blo(dq.w), d7 = bhi(dq.w);
            uint4 q0 = hv0[c8], q1 = hv1[c8], q2 = hv2[c8];
            a0 += d0 * blo(q0.x) + d1 * bhi(q0.x) + d2 * blo(q0.y) + d3 * bhi(q0.y)
                + d4 * blo(q0.z) + d5 * bhi(q0.z) + d6 * blo(q0.w) + d7 * bhi(q0.w);
            a1 += d0 * blo(q1.x) + d1 * bhi(q1.x) + d2 * blo(q1.y) + d3 * bhi(q1.y)
                + d4 * blo(q1.z) + d5 * bhi(q1.z) + d6 * blo(q1.w) + d7 * bhi(q1.w);
            a2 += d0 * blo(q2.x) + d1 * bhi(q2.x) + d2 * blo(q2.y) + d3 * bhi(q2.y)
                + d4 * blo(q2.z) + d5 * bhi(q2.z) + d6 * blo(q2.w) + d7 * bhi(q2.w);
        }
        float sc2 = invn[gpx] * INV_TEMP;
        float s0v = a0 * sc2, s1v = a1 * sc2, s2v = a2 * sc2;
        float ml2 = fmaxf(fmaxf(s0v, s1v), s2v);
        #pragma unroll
        for (int o = 16; o > 0; o >>= 1) ml2 = fmaxf(ml2, __shfl_xor(ml2, o, 32));
        float es = expf(s0v - ml2) + expf(s1v - ml2) + expf(s2v - ml2);
        #pragma unroll
        for (int o = 16; o > 0; o >>= 1) es += __shfl_xor(es, o, 32);
        if (wk == 0) {
            lse_hard[(b << 8) + pidx] = ml2 + logf(es);
            max_hard[(b << 8) + pidx] = ml2;
        }
    }
}

// ---------------------------------------------------------------------------
// k4: masked reduction over all pixels (with grid-point hard fix-up) + final
// loss/accuracy computed by the last block to finish (atomic counter).
// ---------------------------------------------------------------------------
__global__ __launch_bounds__(256) void k4_reduce(
        const float* __restrict__ lse_base, const float* __restrict__ pos_sim,
        const float* __restrict__ max_neg, const float* __restrict__ mask,
        const float* __restrict__ lse_hard, const float* __restrict__ max_hard,
        float* __restrict__ acc, float* __restrict__ out) {
    int i = blockIdx.x * 256 + threadIdx.x;
    float l  = lse_base[i], ps = pos_sim[i], mn = max_neg[i], mk = mask[i];
    int b = i >> 14;
    int n = i & (N_ - 1);
    int y = n >> 7, x = n & 127;
    if (((y & 7) | (x & 7)) == 0) {
        int p = ((y >> 3) << 4) + (x >> 3);
        float lh = lse_hard[(b << 8) + p];
        float mh = max_hard[(b << 8) + p];
        float m = fmaxf(l, lh);
        l  = m + logf(expf(l - m) + expf(lh - m));
        mn = fmaxf(mn, mh);
    }
    float s0 = (l - ps) * mk;
    float s1 = (ps > mn && mk > 0.5f) ? 1.f : 0.f;
    float s2 = mk;
    #pragma unroll
    for (int o = 32; o > 0; o >>= 1) {
        s0 += __shfl_down(s0, o, 64);
        s1 += __shfl_down(s1, o, 64);
        s2 += __shfl_down(s2, o, 64);
    }
    __shared__ float r0[4], r1[4], r2[4];
    int wid = threadIdx.x >> 6;
    if ((threadIdx.x & 63) == 0) { r0[wid] = s0; r1[wid] = s1; r2[wid] = s2; }
    __syncthreads();
    if (threadIdx.x == 0) {
        atomicAdd(&acc[0], r0[0] + r0[1] + r0[2] + r0[3]);
        atomicAdd(&acc[1], r1[0] + r1[1] + r1[2] + r1[3]);
        atomicAdd(&acc[2], r2[0] + r2[1] + r2[2] + r2[3]);
        __threadfence();
        unsigned prev = atomicAdd((unsigned*)&acc[3], 1u);
        if (prev == gridDim.x - 1) {
            float t0 = atomicAdd(&acc[0], 0.f);
            float t1 = atomicAdd(&acc[1], 0.f);
            float t2 = atomicAdd(&acc[2], 0.f);
            float denom = fmaxf(t2, 1.0f);
            out[0] = t0 / denom;
            out[1] = t1 / denom * 100.0f;
        }
    }
}

extern "C" void kernel_launch(void* const* d_in, const int* in_sizes, int n_in,
                              void* d_out, int out_size, void* d_ws, size_t ws_size,
                              hipStream_t stream) {
    const float* rgb     = (const float*)d_in[0];
    const float* dep     = (const float*)d_in[1];
    const float* coords  = (const float*)d_in[2];
    const float* mask    = (const float*)d_in[3];
    const int*   rand_i  = (const int*)d_in[4];
    const int*   hoffu   = (const int*)d_in[5];
    const int*   hoffv   = (const int*)d_in[6];
    float* out = (float*)d_out;
    char*  ws  = (char*)d_ws;

    const size_t RGBT_B = (size_t)B_ * N_ * C_ * 2;      // bf16: 64 MiB
    const size_t PIX_B  = (size_t)B_ * N_ * 4;           // 512 KiB
    unsigned* rgbT  = (unsigned*)ws;
    float* lse_base = (float*)(ws + RGBT_B);
    float* pos_sim  = (float*)(ws + RGBT_B + PIX_B);
    float* max_neg  = (float*)(ws + RGBT_B + 2 * PIX_B);
    float* lse_hard = (float*)(ws + RGBT_B + 3 * PIX_B);
    float* max_hard = (float*)(ws + RGBT_B + 3 * PIX_B + 8192);
    float* acc      = (float*)(ws + RGBT_B + 3 * PIX_B + 2 * 8192);

    hipMemsetAsync(acc, 0, 16, stream);
    k1_rgb_norm_T<<<B_ * (N_ / 64), 256, 0, stream>>>(rgb, rgbT);
    k2_main<<<B_ * (N_ / 64), 256, 0, stream>>>(dep, rgbT, coords, rand_i,
                                                hoffu, hoffv, lse_base, pos_sim,
                                                max_neg, lse_hard, max_hard);
    k4_reduce<<<(B_ * N_) / 256, 256, 0, stream>>>(lse_base, pos_sim, max_neg,
                                                   mask, lse_hard, max_hard,
                                                   acc, out);
}

// Round 6
// 392.576 us; speedup vs baseline: 1.2177x; 1.1372x over previous
//
#include <hip/hip_runtime.h>
#include <cfloat>
#include <math.h>

#define B_ 8
#define C_ 256
#define C2_ (C_/2)            // uints (bf16 pairs) per pixel
#define H_ 128
#define W_ 128
#define N_ (H_*W_)            // 16384
#define NRAND 32
#define NHARD 96
#define NPOS 256
#define INV_TEMP (1.0f/0.07f)

typedef __attribute__((ext_vector_type(8))) short short8;   // 8 bf16 (4 VGPRs)
typedef __attribute__((ext_vector_type(4))) float f32x4;    // MFMA acc

__device__ __forceinline__ unsigned bf16rne(float x) {
    unsigned u = __float_as_uint(x);
    return (u + 0x7FFFu + ((u >> 16) & 1u)) >> 16;
}
__device__ __forceinline__ float blo(unsigned w) { return __uint_as_float(w << 16); }
__device__ __forceinline__ float bhi(unsigned w) { return __uint_as_float(w & 0xFFFF0000u); }

// XCD-aware bijective swizzle for 2048-block grids (2048 = 8 XCD * 256).
// Each XCD owns one batch's contiguous tile range -> DRAM page + L2 locality.
__device__ __forceinline__ int xcd_swz(int bi0) {
    return ((bi0 & 7) << 8) | (bi0 >> 3);
}

// ---------------------------------------------------------------------------
// k1: normalize rgb along C, write transposed bf16 rgbT[b][n][c] (packed u32).
// Register-resident 64ch/thread across the norm reduction; 32KB swizzled LDS
// bounce; fully coalesced uint4 stores. (round-2 best + XCD swizzle)
// ---------------------------------------------------------------------------
__global__ __launch_bounds__(256) void k1_rgb_norm_T(const float* __restrict__ rgb,
                                                     unsigned* __restrict__ rgbT) {
    __shared__ __align__(16) uint4 bounce[64 * 32];   // 32 KB bf16 [px][ch]
    __shared__ float red[4][64];
    __shared__ float invn[64];
    int bi = xcd_swz(blockIdx.x);
    int b  = bi >> 8;                 // 256 tiles per batch
    int p0 = (bi & 255) << 6;
    int t  = threadIdx.x;
    int lane = t & 63, w = t >> 6;

    const float* src = rgb + (size_t)b * C_ * N_ + p0 + lane;
    float v[64];
    float ssq = 0.f;
    #pragma unroll
    for (int k = 0; k < 64; ++k) {
        v[k] = src[(size_t)(w * 64 + k) * N_];
        ssq += v[k] * v[k];
    }
    red[w][lane] = ssq;
    __syncthreads();
    if (t < 64) {
        float s = red[0][t] + red[1][t] + red[2][t] + red[3][t];
        invn[t] = 1.0f / fmaxf(sqrtf(s), 1e-12f);
    }
    __syncthreads();
    float sc = invn[lane];
    int swz = lane & 7;
    #pragma unroll
    for (int j = 0; j < 8; ++j) {
        uint4 q;
        q.x = bf16rne(v[8 * j + 0] * sc) | (bf16rne(v[8 * j + 1] * sc) << 16);
        q.y = bf16rne(v[8 * j + 2] * sc) | (bf16rne(v[8 * j + 3] * sc) << 16);
        q.z = bf16rne(v[8 * j + 4] * sc) | (bf16rne(v[8 * j + 5] * sc) << 16);
        q.w = bf16rne(v[8 * j + 6] * sc) | (bf16rne(v[8 * j + 7] * sc) << 16);
        bounce[lane * 32 + ((w * 8 + j) ^ swz)] = q;
    }
    __syncthreads();
    uint4* dst = (uint4*)(rgbT + (size_t)(b * N_ + p0) * C2_);
    #pragma unroll
    for (int it = 0; it < 8; ++it) {
        int idx = it * 256 + t;
        int px = idx >> 5, j = idx & 31;
        dst[idx] = bounce[px * 32 + (j ^ (px & 7))];
    }
}

// ---------------------------------------------------------------------------
// k2: per 64-pixel tile (round-1/2 best structure). Staging rewritten to
// k1's register pattern: all 64 strided dep loads issue FIRST (max load
// depth), rand gathers overlap their latency, bf16 pack + LDS store after.
// ssq accumulation order identical to before (bitwise-same invn).
// ---------------------------------------------------------------------------
__global__ __launch_bounds__(256) void k2_main(
        const float* __restrict__ dep, const unsigned* __restrict__ rgbT,
        const float* __restrict__ coords, const int* __restrict__ rand_idx,
        float* __restrict__ lse_base, float* __restrict__ pos_out,
        float* __restrict__ maxneg_out, unsigned* __restrict__ depG) {
    __shared__ __align__(16) uint4 dep4[64 * 32];   // 32 KB bf16 [px][ch], swizzled
    __shared__ __align__(16) uint4 rs4[32 * 32];    // 16 KB rand bf16 / later sims f32[64][32]
    __shared__ float red[4][64];
    __shared__ float invn[64];
    int bi = xcd_swz(blockIdx.x);
    int b  = bi >> 8;
    int p0 = (bi & 255) << 6;
    int t  = threadIdx.x;
    int lane = t & 63, w = t >> 6;

    // ---- dep: issue all 64 strided loads first (latency hidden under rand)
    const float* depb = dep + (size_t)b * C_ * N_ + p0 + lane;
    float v[64];
    #pragma unroll
    for (int k = 0; k < 64; ++k) v[k] = depb[(size_t)(w * 64 + k) * N_];

    // ---- stage 32 rand vectors: 16B gather chunks, coalesced 512B per vector
    #pragma unroll
    for (int it = 0; it < 4; ++it) {
        int flat = it * 256 + t;
        int rn = flat >> 5, c8 = flat & 31;
        int idx = rand_idx[b * NRAND + rn];
        const uint4* src = (const uint4*)(rgbT + (size_t)(b * N_ + idx) * C2_);
        rs4[rn * 32 + (c8 ^ (rn & 7))] = src[c8];
    }

    // ---- ssq (same order as before) + bf16 pack into swizzled dep4
    float ssq = 0.f;
    #pragma unroll
    for (int k = 0; k < 64; ++k) ssq += v[k] * v[k];
    int psw = lane & 7;
    #pragma unroll
    for (int i = 0; i < 8; ++i) {
        uint4 q;
        q.x = bf16rne(v[8 * i + 0]) | (bf16rne(v[8 * i + 1]) << 16);
        q.y = bf16rne(v[8 * i + 2]) | (bf16rne(v[8 * i + 3]) << 16);
        q.z = bf16rne(v[8 * i + 4]) | (bf16rne(v[8 * i + 5]) << 16);
        q.w = bf16rne(v[8 * i + 6]) | (bf16rne(v[8 * i + 7]) << 16);
        dep4[lane * 32 + ((w * 8 + i) ^ psw)] = q;
    }
    red[w][lane] = ssq;

    // ---- bilinear setup (issue coord loads before the barrier)
    int px = t >> 2, g = t & 3;
    int n  = p0 + px;
    float xf = coords[(size_t)b * 2 * N_ + n];
    float yf = coords[(size_t)b * 2 * N_ + N_ + n];
    float x0 = floorf(xf), y0 = floorf(yf);
    float wx = xf - x0, wy = yf - y0;
    int ix = (int)x0 + (g & 1);
    int iy = (int)y0 + (g >> 1);
    float wgt = ((g & 1) ? wx : 1.f - wx) * ((g & 2) ? wy : 1.f - wy);
    if (ix < 0 || ix >= W_ || iy < 0 || iy >= H_) wgt = 0.f;
    int ixc = min(max(ix, 0), W_ - 1), iyc = min(max(iy, 0), H_ - 1);
    const uint4* nbr4 = (const uint4*)(rgbT + (size_t)(b * N_ + iyc * W_ + ixc) * C2_);

    __syncthreads();                          // all LDS staged
    if (t < 64) {
        float s = red[0][t] + red[1][t] + red[2][t] + red[3][t];
        invn[t] = 1.0f / fmaxf(sqrtf(s), 1e-12f);
    }

    // ---- MFMA: A = dep rows (M=px), B = rand vectors (N=rand), K=256
    f32x4 acc0 = {0.f, 0.f, 0.f, 0.f};
    f32x4 acc1 = {0.f, 0.f, 0.f, 0.f};
    int l15 = lane & 15, l4 = lane >> 4;
    int pxA = (w << 4) + l15;
    const short8* lds8 = (const short8*)dep4;
    const short8* rnd8 = (const short8*)rs4;
    #pragma unroll
    for (int kc = 0; kc < 8; ++kc) {
        int c8 = kc * 4 + l4;
        short8 a  = lds8[pxA * 32 + (c8 ^ (pxA & 7))];
        short8 b0 = rnd8[l15 * 32 + (c8 ^ (l15 & 7))];
        short8 b1 = rnd8[(16 + l15) * 32 + (c8 ^ (l15 & 7))];
        acc0 = __builtin_amdgcn_mfma_f32_16x16x32_bf16(a, b0, acc0, 0, 0, 0);
        acc1 = __builtin_amdgcn_mfma_f32_16x16x32_bf16(a, b1, acc1, 0, 0, 0);
    }

    // ---- pos: dot(dep_px, nbr_g) on VALU (bf16 unpack)
    float accN = 0.f;
    const uint4* drow = dep4 + (size_t)px * 32;
    int dsw = px & 7;
    #pragma unroll 4
    for (int c8 = 0; c8 < 32; ++c8) {
        uint4 dq = drow[c8 ^ dsw];
        uint4 rq = nbr4[c8];
        accN += blo(dq.x) * blo(rq.x) + bhi(dq.x) * bhi(rq.x)
              + blo(dq.y) * blo(rq.y) + bhi(dq.y) * bhi(rq.y)
              + blo(dq.z) * blo(rq.z) + bhi(dq.z) * bhi(rq.z)
              + blo(dq.w) * blo(rq.w) + bhi(dq.w) * bhi(rq.w);
    }
    __syncthreads();                          // MFMA+pos reads done; rs4 reusable

    // ---- dump raw sims -> rs4 as f32 [64][32], n-index XOR'd by (prow&3)<<2
    float* simsF = (float*)rs4;
    #pragma unroll
    for (int r = 0; r < 4; ++r) {
        int prow = (w << 4) + (l4 << 2) + r;   // prow&3 == r
        int swn = r << 2;
        simsF[prow * 32 + (l15 ^ swn)]        = acc0[r];
        simsF[prow * 32 + (16 + (l15 ^ swn))] = acc1[r];
    }
    __syncthreads();

    // ---- epilogue per (px, g): thread g owns rand [8g, 8g+8)
    float scale = invn[px] * INV_TEMP;
    float pp = accN * wgt;
    pp += __shfl_xor(pp, 1, 4);
    pp += __shfl_xor(pp, 2, 4);
    float pos = pp * scale;
    const float4* sf = (const float4*)simsF;
    int fsw = px & 3;
    float4 ra = sf[px * 8 + ((g * 2) ^ fsw)];
    float4 rb = sf[px * 8 + (((g * 2) ^ fsw) ^ 1)];
    float r[8] = {ra.x, ra.y, ra.z, ra.w, rb.x, rb.y, rb.z, rb.w};
    float ml = -FLT_MAX;
    #pragma unroll
    for (int j = 0; j < 8; ++j) { r[j] *= scale; ml = fmaxf(ml, r[j]); }
    ml = fmaxf(ml, __shfl_xor(ml, 1, 4));
    ml = fmaxf(ml, __shfl_xor(ml, 2, 4));
    float mneg = ml;
    float mall = fmaxf(mneg, pos);
    float se = 0.f;
    #pragma unroll
    for (int j = 0; j < 8; ++j) se += expf(r[j] - mall);
    se += __shfl_xor(se, 1, 4);
    se += __shfl_xor(se, 2, 4);
    if (g == 0) {
        float lse = mall + logf(se + expf(pos - mall));
        size_t o = (size_t)b * N_ + n;
        lse_base[o]   = lse;
        pos_out[o]    = pos;
        maxneg_out[o] = mneg;
    }

    // ---- depG: normalized bf16 dep vectors for the 8 grid pixels of this tile
    int y = p0 >> 7;                  // 64-px tile = half a row -> y uniform
    if ((y & 7) == 0) {
        int m = t >> 5, u = t & 31;
        int gpx = m * 8;              // grid pixels at px = 0,8,...,56
        int gx  = (p0 & 127) + gpx;
        int p   = ((y >> 3) << 4) + (gx >> 3);
        float sc = invn[gpx];
        const unsigned* srow = (const unsigned*)(dep4 + (size_t)gpx * 32);
        int xsw = (gpx & 7) << 2;     // chunk-swizzle expressed in u32 units
        unsigned* dst = depG + (size_t)((b << 8) + p) * 128;
        #pragma unroll
        for (int it = 0; it < 4; ++it) {
            int uu = u + it * 32;
            unsigned wv = srow[uu ^ xsw];
            dst[uu] = bf16rne(blo(wv) * sc) | (bf16rne(bhi(wv) * sc) << 16);
        }
    }
}

// ---------------------------------------------------------------------------
// k3: hard negatives. 192-thread blocks, 2 threads per hard negative (16
// uint4 gathers each, fully unrolled -> all loads in flight), pairwise
// combine via __shfl_xor width-2. dep vector from depG (round-2 proven).
// ---------------------------------------------------------------------------
__global__ __launch_bounds__(192) void k3_hard(
        const unsigned* __restrict__ depG, const unsigned* __restrict__ rgbT,
        const float* __restrict__ coords, const int* __restrict__ hoffu,
        const int* __restrict__ hoffv, float* __restrict__ lse_hard,
        float* __restrict__ max_hard) {
    __shared__ __align__(16) float dv[256];
    __shared__ float sm_[3], ss_[3];
    int bp = xcd_swz(blockIdx.x);
    int b = bp >> 8, p = bp & 255;
    int gy = (p >> 4) * 8, gx = (p & 15) * 8;
    int nn = gy * W_ + gx;
    int t  = threadIdx.x;
    if (t < 128) {
        unsigned wv = depG[(size_t)bp * 128 + t];
        dv[2 * t]     = blo(wv);
        dv[2 * t + 1] = bhi(wv);
    }
    float pu = coords[(size_t)b * 2 * N_ + nn];
    float pv = coords[(size_t)b * 2 * N_ + N_ + nn];
    int iu = (int)fminf(fmaxf(pu, 0.f), (float)(W_ - 1));
    int iv = (int)fminf(fmaxf(pv, 0.f), (float)(H_ - 1));
    int h = t >> 1, half = t & 1;     // h in [0,96): every lane is active
    int ou = hoffu[((size_t)b * NHARD + h) * NPOS + p];
    int ov = hoffv[((size_t)b * NHARD + h) * NPOS + p];
    __syncthreads();
    if (ou == 0 && ov == 0) ou = 1;
    int hu = min(max(iu + ou, 0), W_ - 1);
    int hv = min(max(iv + ov, 0), H_ - 1);
    const uint4* hvec = (const uint4*)(rgbT + (size_t)(b * N_ + hv * W_ + hu) * C2_)
                        + half * 16;
    const float4* dvv = (const float4*)dv + half * 32;
    float acc = 0.f;
    #pragma unroll
    for (int c8 = 0; c8 < 16; ++c8) {
        uint4 q = hvec[c8];
        float4 d0 = dvv[c8 * 2];
        float4 d1 = dvv[c8 * 2 + 1];
        acc += d0.x * blo(q.x) + d0.y * bhi(q.x)
             + d0.z * blo(q.y) + d0.w * bhi(q.y)
             + d1.x * blo(q.z) + d1.y * bhi(q.z)
             + d1.z * blo(q.w) + d1.w * bhi(q.w);
    }
    float sim = (acc + __shfl_xor(acc, 1, 2)) * INV_TEMP;
    float m = sim;
    #pragma unroll
    for (int o = 32; o > 0; o >>= 1) m = fmaxf(m, __shfl_xor(m, o, 64));
    int wid = t >> 6;
    if ((t & 63) == 0) sm_[wid] = m;
    __syncthreads();
    float mm = fmaxf(fmaxf(sm_[0], sm_[1]), sm_[2]);
    float e = (half == 0) ? expf(sim - mm) : 0.f;   // dedup the pair
    #pragma unroll
    for (int o = 32; o > 0; o >>= 1) e += __shfl_xor(e, o, 64);
    if ((t & 63) == 0) ss_[wid] = e;
    __syncthreads();
    if (t == 0) {
        lse_hard[bp] = mm + logf(ss_[0] + ss_[1] + ss_[2]);
        max_hard[bp] = mm;
    }
}

// ---------------------------------------------------------------------------
// k4: masked reduction over all pixels (with grid-point hard fix-up) + final
// loss/accuracy computed by the last block to finish (atomic counter).
// ---------------------------------------------------------------------------
__global__ __launch_bounds__(256) void k4_reduce(
        const float* __restrict__ lse_base, const float* __restrict__ pos_sim,
        const float* __restrict__ max_neg, const float* __restrict__ mask,
        const float* __restrict__ lse_hard, const float* __restrict__ max_hard,
        float* __restrict__ acc, float* __restrict__ out) {
    int i = blockIdx.x * 256 + threadIdx.x;
    float l  = lse_base[i], ps = pos_sim[i], mn = max_neg[i], mk = mask[i];
    int b = i >> 14;
    int n = i & (N_ - 1);
    int y = n >> 7, x = n & 127;
    if (((y & 7) | (x & 7)) == 0) {
        int p = ((y >> 3) << 4) + (x >> 3);
        float lh = lse_hard[(b << 8) + p];
        float mh = max_hard[(b << 8) + p];
        float m = fmaxf(l, lh);
        l  = m + logf(expf(l - m) + expf(lh - m));
        mn = fmaxf(mn, mh);
    }
    float s0 = (l - ps) * mk;
    float s1 = (ps > mn && mk > 0.5f) ? 1.f : 0.f;
    float s2 = mk;
    #pragma unroll
    for (int o = 32; o > 0; o >>= 1) {
        s0 += __shfl_down(s0, o, 64);
        s1 += __shfl_down(s1, o, 64);
        s2 += __shfl_down(s2, o, 64);
    }
    __shared__ float r0[4], r1[4], r2[4];
    int wid = threadIdx.x >> 6;
    if ((threadIdx.x & 63) == 0) { r0[wid] = s0; r1[wid] = s1; r2[wid] = s2; }
    __syncthreads();
    if (threadIdx.x == 0) {
        atomicAdd(&acc[0], r0[0] + r0[1] + r0[2] + r0[3]);
        atomicAdd(&acc[1], r1[0] + r1[1] + r1[2] + r1[3]);
        atomicAdd(&acc[2], r2[0] + r2[1] + r2[2] + r2[3]);
        __threadfence();
        unsigned prev = atomicAdd((unsigned*)&acc[3], 1u);
        if (prev == gridDim.x - 1) {
            float t0 = atomicAdd(&acc[0], 0.f);
            float t1 = atomicAdd(&acc[1], 0.f);
            float t2 = atomicAdd(&acc[2], 0.f);
            float denom = fmaxf(t2, 1.0f);
            out[0] = t0 / denom;
            out[1] = t1 / denom * 100.0f;
        }
    }
}

extern "C" void kernel_launch(void* const* d_in, const int* in_sizes, int n_in,
                              void* d_out, int out_size, void* d_ws, size_t ws_size,
                              hipStream_t stream) {
    const float* rgb     = (const float*)d_in[0];
    const float* dep     = (const float*)d_in[1];
    const float* coords  = (const float*)d_in[2];
    const float* mask    = (const float*)d_in[3];
    const int*   rand_i  = (const int*)d_in[4];
    const int*   hoffu   = (const int*)d_in[5];
    const int*   hoffv   = (const int*)d_in[6];
    float* out = (float*)d_out;
    char*  ws  = (char*)d_ws;

    const size_t RGBT_B = (size_t)B_ * N_ * C_ * 2;      // bf16: 64 MiB
    const size_t PIX_B  = (size_t)B_ * N_ * 4;           // 512 KiB
    unsigned* rgbT  = (unsigned*)ws;
    float* lse_base = (float*)(ws + RGBT_B);
    float* pos_sim  = (float*)(ws + RGBT_B + PIX_B);
    float* max_neg  = (float*)(ws + RGBT_B + 2 * PIX_B);
    float* lse_hard = (float*)(ws + RGBT_B + 3 * PIX_B);
    float* max_hard = (float*)(ws + RGBT_B + 3 * PIX_B + 8192);
    float* acc      = (float*)(ws + RGBT_B + 3 * PIX_B + 2 * 8192);
    unsigned* depG  = (unsigned*)(ws + RGBT_B + 3 * PIX_B + 2 * 8192 + 1024); // 1 MB

    hipMemsetAsync(acc, 0, 16, stream);
    k1_rgb_norm_T<<<B_ * (N_ / 64), 256, 0, stream>>>(rgb, rgbT);
    k2_main<<<B_ * (N_ / 64), 256, 0, stream>>>(dep, rgbT, coords, rand_i,
                                                lse_base, pos_sim, max_neg, depG);
    k3_hard<<<B_ * NPOS, 192, 0, stream>>>(depG, rgbT, coords, hoffu, hoffv,
                                           lse_hard, max_hard);
    k4_reduce<<<(B_ * N_) / 256, 256, 0, stream>>>(lse_base, pos_sim, max_neg,
                                                   mask, lse_hard, max_hard,
                                                   acc, out);
}

// Round 7
// 382.461 us; speedup vs baseline: 1.2499x; 1.0264x over previous
//
#include <hip/hip_runtime.h>
#include <cfloat>
#include <math.h>

#define B_ 8
#define C_ 256
#define C2_ (C_/2)            // uints (bf16 pairs) per pixel
#define H_ 128
#define W_ 128
#define N_ (H_*W_)            // 16384
#define NRAND 32
#define NHARD 96
#define NPOS 256
#define INV_TEMP (1.0f/0.07f)

typedef __attribute__((ext_vector_type(8))) short short8;   // 8 bf16 (4 VGPRs)
typedef __attribute__((ext_vector_type(4))) float f32x4;    // MFMA acc

__device__ __forceinline__ unsigned bf16rne(float x) {
    unsigned u = __float_as_uint(x);
    return (u + 0x7FFFu + ((u >> 16) & 1u)) >> 16;
}
__device__ __forceinline__ float blo(unsigned w) { return __uint_as_float(w << 16); }
__device__ __forceinline__ float bhi(unsigned w) { return __uint_as_float(w & 0xFFFF0000u); }

// ---------------------------------------------------------------------------
// k1: normalize rgb along C, write transposed bf16 rgbT[b][n][c] (packed u32).
// Register-resident 64ch/thread; 32KB swizzled LDS bounce; coalesced uint4
// stores. (round-2 measured version, no blockIdx swizzle)
// ---------------------------------------------------------------------------
__global__ __launch_bounds__(256) void k1_rgb_norm_T(const float* __restrict__ rgb,
                                                     unsigned* __restrict__ rgbT) {
    __shared__ __align__(16) uint4 bounce[64 * 32];   // 32 KB bf16 [px][ch]
    __shared__ float red[4][64];
    __shared__ float invn[64];
    int bi = blockIdx.x;
    int b  = bi >> 8;                 // 256 tiles per batch
    int p0 = (bi & 255) << 6;
    int t  = threadIdx.x;
    int lane = t & 63, w = t >> 6;

    const float* src = rgb + (size_t)b * C_ * N_ + p0 + lane;
    float v[64];
    float ssq = 0.f;
    #pragma unroll
    for (int k = 0; k < 64; ++k) {
        v[k] = src[(size_t)(w * 64 + k) * N_];
        ssq += v[k] * v[k];
    }
    red[w][lane] = ssq;
    __syncthreads();
    if (t < 64) {
        float s = red[0][t] + red[1][t] + red[2][t] + red[3][t];
        invn[t] = 1.0f / fmaxf(sqrtf(s), 1e-12f);
    }
    __syncthreads();
    float sc = invn[lane];
    int swz = lane & 7;
    #pragma unroll
    for (int j = 0; j < 8; ++j) {
        uint4 q;
        q.x = bf16rne(v[8 * j + 0] * sc) | (bf16rne(v[8 * j + 1] * sc) << 16);
        q.y = bf16rne(v[8 * j + 2] * sc) | (bf16rne(v[8 * j + 3] * sc) << 16);
        q.z = bf16rne(v[8 * j + 4] * sc) | (bf16rne(v[8 * j + 5] * sc) << 16);
        q.w = bf16rne(v[8 * j + 6] * sc) | (bf16rne(v[8 * j + 7] * sc) << 16);
        bounce[lane * 32 + ((w * 8 + j) ^ swz)] = q;
    }
    __syncthreads();
    uint4* dst = (uint4*)(rgbT + (size_t)(b * N_ + p0) * C2_);
    #pragma unroll
    for (int it = 0; it < 8; ++it) {
        int idx = it * 256 + t;
        int px = idx >> 5, j = idx & 31;
        dst[idx] = bounce[px * 32 + (j ^ (px & 7))];
    }
}

// ---------------------------------------------------------------------------
// k2: 32-PIXEL tile (was 64). LDS 50.7KB -> ~34KB => 4 blocks/CU (16 waves,
// 50% cap, was 37.5%): +33% resident waves for the latency-bound staging.
// MFMA: 4 waves, wave w owns (Mhalf = w&1)*16 px x (Nhalf = w>>1)*16 rand,
// K=256 in 8 steps. Epilogue: 8 threads/px (4 bilinear nbrs x 2 ch-halves).
// Staging is the round-1 interleaved 8-chunk pattern (measured best).
// ---------------------------------------------------------------------------
__global__ __launch_bounds__(256) void k2_main(
        const float* __restrict__ dep, const unsigned* __restrict__ rgbT,
        const float* __restrict__ coords, const int* __restrict__ rand_idx,
        float* __restrict__ lse_base, float* __restrict__ pos_out,
        float* __restrict__ maxneg_out, unsigned* __restrict__ depG) {
    __shared__ __align__(16) uint4 dep4[32 * 32];   // 16 KB bf16 [px][chunk], swizzled
    __shared__ __align__(16) uint4 rs4[32 * 32];    // 16 KB rand bf16 / later sims f32[32][32]
    __shared__ float red[8][32];
    __shared__ float invn[32];
    int bi = blockIdx.x;
    int b  = bi >> 9;
    int p0 = (bi & 511) << 5;
    int t  = threadIdx.x;
    int lane = t & 63, w = t >> 6;

    // ---- stage 32 rand vectors: 16B gather chunks, coalesced 512B per vector
    #pragma unroll
    for (int it = 0; it < 4; ++it) {
        int flat = it * 256 + t;
        int rn = flat >> 5, c8 = flat & 31;
        int idx = rand_idx[b * NRAND + rn];
        const uint4* src = (const uint4*)(rgbT + (size_t)(b * N_ + idx) * C2_);
        rs4[rn * 32 + (c8 ^ (rn & 7))] = src[c8];
    }

    // ---- stage dep: thread (px32 = t&31, cg = t>>5) -> pixel p0+px32,
    //      channels [32cg, 32cg+32), interleaved 8-chunk pattern
    int px32 = t & 31, cg = t >> 5;
    const float* depb = dep + (size_t)b * C_ * N_ + p0 + px32;
    float ssq = 0.f;
    int psw = px32 & 7;
    #pragma unroll 2
    for (int i = 0; i < 4; ++i) {
        int c0 = cg * 32 + i * 8;
        float v[8];
        #pragma unroll
        for (int k = 0; k < 8; ++k) {
            v[k] = depb[(size_t)(c0 + k) * N_];
            ssq += v[k] * v[k];
        }
        uint4 q;
        q.x = bf16rne(v[0]) | (bf16rne(v[1]) << 16);
        q.y = bf16rne(v[2]) | (bf16rne(v[3]) << 16);
        q.z = bf16rne(v[4]) | (bf16rne(v[5]) << 16);
        q.w = bf16rne(v[6]) | (bf16rne(v[7]) << 16);
        dep4[px32 * 32 + ((cg * 4 + i) ^ psw)] = q;
    }
    red[cg][px32] = ssq;

    // ---- bilinear setup: px = t>>3, j = t&7 (g = j&3 nbr, hc = j>>2 ch-half)
    int px = t >> 3, j = t & 7, g = j & 3, hc = j >> 2;
    int n  = p0 + px;
    float xf = coords[(size_t)b * 2 * N_ + n];
    float yf = coords[(size_t)b * 2 * N_ + N_ + n];
    float x0 = floorf(xf), y0 = floorf(yf);
    float wx = xf - x0, wy = yf - y0;
    int ix = (int)x0 + (g & 1);
    int iy = (int)y0 + (g >> 1);
    float wgt = ((g & 1) ? wx : 1.f - wx) * ((g & 2) ? wy : 1.f - wy);
    if (ix < 0 || ix >= W_ || iy < 0 || iy >= H_) wgt = 0.f;
    int ixc = min(max(ix, 0), W_ - 1), iyc = min(max(iy, 0), H_ - 1);
    const uint4* nbr4 = (const uint4*)(rgbT + (size_t)(b * N_ + iyc * W_ + ixc) * C2_);

    __syncthreads();                          // all LDS staged
    if (t < 32) {
        float s = 0.f;
        #pragma unroll
        for (int gg = 0; gg < 8; ++gg) s += red[gg][t];
        invn[t] = 1.0f / fmaxf(sqrtf(s), 1e-12f);
    }

    // ---- MFMA: wave w -> rows [16(w&1),+16) x rand [16(w>>1),+16), K=256
    f32x4 acc0 = {0.f, 0.f, 0.f, 0.f};
    int l15 = lane & 15, l4 = lane >> 4;
    int mh = w & 1, nh = w >> 1;
    int arow = mh * 16 + l15;
    int brow = nh * 16 + l15;
    const short8* lds8 = (const short8*)dep4;
    const short8* rnd8 = (const short8*)rs4;
    #pragma unroll
    for (int kc = 0; kc < 8; ++kc) {
        int c8 = kc * 4 + l4;
        short8 a  = lds8[arow * 32 + (c8 ^ (arow & 7))];
        short8 b0 = rnd8[brow * 32 + (c8 ^ (brow & 7))];
        acc0 = __builtin_amdgcn_mfma_f32_16x16x32_bf16(a, b0, acc0, 0, 0, 0);
    }

    // ---- pos: dot(dep_px, nbr_g) over channel-half hc (16 chunks)
    float accN = 0.f;
    const uint4* drow = dep4 + (size_t)px * 32;
    int dsw = px & 7;
    #pragma unroll 4
    for (int c = 0; c < 16; ++c) {
        int cc = hc * 16 + c;
        uint4 dq = drow[cc ^ dsw];
        uint4 rq = nbr4[cc];
        accN += blo(dq.x) * blo(rq.x) + bhi(dq.x) * bhi(rq.x)
              + blo(dq.y) * blo(rq.y) + bhi(dq.y) * bhi(rq.y)
              + blo(dq.z) * blo(rq.z) + bhi(dq.z) * bhi(rq.z)
              + blo(dq.w) * blo(rq.w) + bhi(dq.w) * bhi(rq.w);
    }
    __syncthreads();                          // MFMA rand reads done; rs4 reusable

    // ---- dump raw sims -> rs4 as f32 [32][32], float4-group XOR-swizzled
    // D layout: row = mh*16 + l4*4 + reg, col = nh*16 + l15
    float* simsF = (float*)rs4;
    #pragma unroll
    for (int r = 0; r < 4; ++r) {
        int row = mh * 16 + (l4 << 2) + r;
        int c   = nh * 16 + l15;
        int f4  = (c >> 2) ^ (row & 7);
        simsF[row * 32 + f4 * 4 + (c & 3)] = acc0[r];
    }
    __syncthreads();

    // ---- epilogue per (px, j): thread j owns rand [4j, 4j+4)
    float scale = invn[px] * INV_TEMP;
    float pp = accN * wgt;
    pp += __shfl_xor(pp, 1, 8);
    pp += __shfl_xor(pp, 2, 8);
    pp += __shfl_xor(pp, 4, 8);
    float pos = pp * scale;
    const float4* sf = (const float4*)simsF;
    float4 ra = sf[px * 8 + (j ^ (px & 7))];
    float r4[4] = {ra.x, ra.y, ra.z, ra.w};
    float ml = -FLT_MAX;
    #pragma unroll
    for (int e = 0; e < 4; ++e) { r4[e] *= scale; ml = fmaxf(ml, r4[e]); }
    ml = fmaxf(ml, __shfl_xor(ml, 1, 8));
    ml = fmaxf(ml, __shfl_xor(ml, 2, 8));
    ml = fmaxf(ml, __shfl_xor(ml, 4, 8));
    float mneg = ml;
    float mall = fmaxf(mneg, pos);
    float se = 0.f;
    #pragma unroll
    for (int e = 0; e < 4; ++e) se += expf(r4[e] - mall);
    se += __shfl_xor(se, 1, 8);
    se += __shfl_xor(se, 2, 8);
    se += __shfl_xor(se, 4, 8);
    if (j == 0) {
        float lse = mall + logf(se + expf(pos - mall));
        size_t o = (size_t)b * N_ + n;
        lse_base[o]   = lse;
        pos_out[o]    = pos;
        maxneg_out[o] = mneg;
    }

    // ---- depG: normalized bf16 dep vectors for the 4 grid pixels of this tile
    int y = p0 >> 7;                  // 32-px tile = quarter row -> y uniform
    if ((y & 7) == 0) {
        int m = t >> 6, u = t & 63;
        int gpx = m * 8;              // grid pixels at px = 0,8,16,24
        int gx  = (p0 & 127) + gpx;
        int p   = ((y >> 3) << 4) + (gx >> 3);
        float sc = invn[gpx];
        const unsigned* srow = (const unsigned*)(dep4 + (size_t)gpx * 32); // gpx&7==0: linear
        unsigned* dst = depG + (size_t)((b << 8) + p) * 128;
        #pragma unroll
        for (int it = 0; it < 2; ++it) {
            int uu = u + it * 64;
            unsigned wv = srow[uu];
            dst[uu] = bf16rne(blo(wv) * sc) | (bf16rne(bhi(wv) * sc) << 16);
        }
    }
}

// ---------------------------------------------------------------------------
// k3: hard negatives. 192-thread blocks, 2 threads per hard negative (16
// uint4 gathers each), pairwise combine via __shfl_xor width-2. dep vector
// from depG. (round-2 measured version, no blockIdx swizzle)
// ---------------------------------------------------------------------------
__global__ __launch_bounds__(192) void k3_hard(
        const unsigned* __restrict__ depG, const unsigned* __restrict__ rgbT,
        const float* __restrict__ coords, const int* __restrict__ hoffu,
        const int* __restrict__ hoffv, float* __restrict__ lse_hard,
        float* __restrict__ max_hard) {
    __shared__ __align__(16) float dv[256];
    __shared__ float sm_[3], ss_[3];
    int bp = blockIdx.x;
    int b = bp >> 8, p = bp & 255;
    int gy = (p >> 4) * 8, gx = (p & 15) * 8;
    int nn = gy * W_ + gx;
    int t  = threadIdx.x;
    if (t < 128) {
        unsigned wv = depG[(size_t)bp * 128 + t];
        dv[2 * t]     = blo(wv);
        dv[2 * t + 1] = bhi(wv);
    }
    float pu = coords[(size_t)b * 2 * N_ + nn];
    float pv = coords[(size_t)b * 2 * N_ + N_ + nn];
    int iu = (int)fminf(fmaxf(pu, 0.f), (float)(W_ - 1));
    int iv = (int)fminf(fmaxf(pv, 0.f), (float)(H_ - 1));
    int h = t >> 1, half = t & 1;     // h in [0,96): every lane is active
    int ou = hoffu[((size_t)b * NHARD + h) * NPOS + p];
    int ov = hoffv[((size_t)b * NHARD + h) * NPOS + p];
    __syncthreads();
    if (ou == 0 && ov == 0) ou = 1;
    int hu = min(max(iu + ou, 0), W_ - 1);
    int hv = min(max(iv + ov, 0), H_ - 1);
    const uint4* hvec = (const uint4*)(rgbT + (size_t)(b * N_ + hv * W_ + hu) * C2_)
                        + half * 16;
    const float4* dvv = (const float4*)dv + half * 32;
    float acc = 0.f;
    #pragma unroll 4
    for (int c8 = 0; c8 < 16; ++c8) {
        uint4 q = hvec[c8];
        float4 d0 = dvv[c8 * 2];
        float4 d1 = dvv[c8 * 2 + 1];
        acc += d0.x * blo(q.x) + d0.y * bhi(q.x)
             + d0.z * blo(q.y) + d0.w * bhi(q.y)
             + d1.x * blo(q.z) + d1.y * bhi(q.z)
             + d1.z * blo(q.w) + d1.w * bhi(q.w);
    }
    float sim = (acc + __shfl_xor(acc, 1, 2)) * INV_TEMP;
    float m = sim;
    #pragma unroll
    for (int o = 32; o > 0; o >>= 1) m = fmaxf(m, __shfl_xor(m, o, 64));
    int wid = t >> 6;
    if ((t & 63) == 0) sm_[wid] = m;
    __syncthreads();
    float mm = fmaxf(fmaxf(sm_[0], sm_[1]), sm_[2]);
    float e = (half == 0) ? expf(sim - mm) : 0.f;   // dedup the pair
    #pragma unroll
    for (int o = 32; o > 0; o >>= 1) e += __shfl_xor(e, o, 64);
    if ((t & 63) == 0) ss_[wid] = e;
    __syncthreads();
    if (t == 0) {
        lse_hard[bp] = mm + logf(ss_[0] + ss_[1] + ss_[2]);
        max_hard[bp] = mm;
    }
}

// ---------------------------------------------------------------------------
// k4: masked reduction over all pixels (with grid-point hard fix-up) + final
// loss/accuracy computed by the last block to finish (atomic counter).
// ---------------------------------------------------------------------------
__global__ __launch_bounds__(256) void k4_reduce(
        const float* __restrict__ lse_base, const float* __restrict__ pos_sim,
        const float* __restrict__ max_neg, const float* __restrict__ mask,
        const float* __restrict__ lse_hard, const float* __restrict__ max_hard,
        float* __restrict__ acc, float* __restrict__ out) {
    int i = blockIdx.x * 256 + threadIdx.x;
    float l  = lse_base[i], ps = pos_sim[i], mn = max_neg[i], mk = mask[i];
    int b = i >> 14;
    int n = i & (N_ - 1);
    int y = n >> 7, x = n & 127;
    if (((y & 7) | (x & 7)) == 0) {
        int p = ((y >> 3) << 4) + (x >> 3);
        float lh = lse_hard[(b << 8) + p];
        float mh = max_hard[(b << 8) + p];
        float m = fmaxf(l, lh);
        l  = m + logf(expf(l - m) + expf(lh - m));
        mn = fmaxf(mn, mh);
    }
    float s0 = (l - ps) * mk;
    float s1 = (ps > mn && mk > 0.5f) ? 1.f : 0.f;
    float s2 = mk;
    #pragma unroll
    for (int o = 32; o > 0; o >>= 1) {
        s0 += __shfl_down(s0, o, 64);
        s1 += __shfl_down(s1, o, 64);
        s2 += __shfl_down(s2, o, 64);
    }
    __shared__ float r0[4], r1[4], r2[4];
    int wid = threadIdx.x >> 6;
    if ((threadIdx.x & 63) == 0) { r0[wid] = s0; r1[wid] = s1; r2[wid] = s2; }
    __syncthreads();
    if (threadIdx.x == 0) {
        atomicAdd(&acc[0], r0[0] + r0[1] + r0[2] + r0[3]);
        atomicAdd(&acc[1], r1[0] + r1[1] + r1[2] + r1[3]);
        atomicAdd(&acc[2], r2[0] + r2[1] + r2[2] + r2[3]);
        __threadfence();
        unsigned prev = atomicAdd((unsigned*)&acc[3], 1u);
        if (prev == gridDim.x - 1) {
            float t0 = atomicAdd(&acc[0], 0.f);
            float t1 = atomicAdd(&acc[1], 0.f);
            float t2 = atomicAdd(&acc[2], 0.f);
            float denom = fmaxf(t2, 1.0f);
            out[0] = t0 / denom;
            out[1] = t1 / denom * 100.0f;
        }
    }
}

extern "C" void kernel_launch(void* const* d_in, const int* in_sizes, int n_in,
                              void* d_out, int out_size, void* d_ws, size_t ws_size,
                              hipStream_t stream) {
    const float* rgb     = (const float*)d_in[0];
    const float* dep     = (const float*)d_in[1];
    const float* coords  = (const float*)d_in[2];
    const float* mask    = (const float*)d_in[3];
    const int*   rand_i  = (const int*)d_in[4];
    const int*   hoffu   = (const int*)d_in[5];
    const int*   hoffv   = (const int*)d_in[6];
    float* out = (float*)d_out;
    char*  ws  = (char*)d_ws;

    const size_t RGBT_B = (size_t)B_ * N_ * C_ * 2;      // bf16: 64 MiB
    const size_t PIX_B  = (size_t)B_ * N_ * 4;           // 512 KiB
    unsigned* rgbT  = (unsigned*)ws;
    float* lse_base = (float*)(ws + RGBT_B);
    float* pos_sim  = (float*)(ws + RGBT_B + PIX_B);
    float* max_neg  = (float*)(ws + RGBT_B + 2 * PIX_B);
    float* lse_hard = (float*)(ws + RGBT_B + 3 * PIX_B);
    float* max_hard = (float*)(ws + RGBT_B + 3 * PIX_B + 8192);
    float* acc      = (float*)(ws + RGBT_B + 3 * PIX_B + 2 * 8192);
    unsigned* depG  = (unsigned*)(ws + RGBT_B + 3 * PIX_B + 2 * 8192 + 1024); // 1 MB

    hipMemsetAsync(acc, 0, 16, stream);
    k1_rgb_norm_T<<<B_ * (N_ / 64), 256, 0, stream>>>(rgb, rgbT);
    k2_main<<<B_ * (N_ / 32), 256, 0, stream>>>(dep, rgbT, coords, rand_i,
                                                lse_base, pos_sim, max_neg, depG);
    k3_hard<<<B_ * NPOS, 192, 0, stream>>>(depG, rgbT, coords, hoffu, hoffv,
                                           lse_hard, max_hard);
    k4_reduce<<<(B_ * N_) / 256, 256, 0, stream>>>(lse_base, pos_sim, max_neg,
                                                   mask, lse_hard, max_hard,
                                                   acc, out);
}